// Round 1
// baseline (410.554 us; speedup 1.0000x reference)
//
#include <hip/hip_runtime.h>
#include <math.h>

#define NEG 0.2f
#define EPSV 1e-5f

typedef _Float16 v8h __attribute__((ext_vector_type(8)));
typedef _Float16 v4h __attribute__((ext_vector_type(4)));
typedef _Float16 v2h __attribute__((ext_vector_type(2)));
typedef __fp16   f16x2 __attribute__((ext_vector_type(2)));
typedef float    v4f __attribute__((ext_vector_type(4)));

__device__ __forceinline__ float lrelu(float v) { return fmaxf(v, NEG * v); }
__device__ __forceinline__ v4f lrelu4(v4f v) {
    return __builtin_elementwise_max(v, v * NEG);
}
__device__ __forceinline__ v2h lreluh2(v2h v) {
    return __builtin_elementwise_max(v, v * (_Float16)NEG);
}

// cvt_pkrtz returns __fp16x2; bit-cast to _Float16x2 (same layout)
__device__ __forceinline__ v2h pk(float a, float b) {
    union { f16x2 i; v2h o; } u;
    u.i = __builtin_amdgcn_cvt_pkrtz(a, b);
    return u.o;
}

#define MFMA32(a, b, c) __builtin_amdgcn_mfma_f32_16x16x32_f16((a), (b), (c), 0, 0, 0)
#define MFMA16(a, b, c) __builtin_amdgcn_mfma_f32_16x16x16f16((a), (b), (c), 0, 0, 0)

// Round 15: cut VALU issue + serial latency (VALUBusy ~60%, MfmaUtil 17%,
// HBM 8% -> issue/latency-bound).
// (1) Gate reduction via MFMA: ghp is already in 16x16x16 B-operand layout
//     (lane(p,q) holds h=4q+r for col p). One MFMA with broadcast A-frag
//     A[row][k]=gate_w2[k] replaces 2 serial __shfl_xor + ~10 VALU per k.
// (2) Per-lane channel pointers + dwordx2 k-pair loads: lanes only load the
//     4 channel streams they consume (hi lanes: c4,c5 + const (1,0) f16 pair).
//     VMEM 120 -> 40 instr/lane; B-frag build 4 cndmask -> 1.
// (3) k-loop unrolled x2 -> static even/odd LDS buffers, no sel arithmetic.
// LDS unchanged 37,888 B -> 4 blocks/CU (grid is exactly 4 blocks/CU).
// VGPR est ~85; __launch_bounds__(256,4) pins allocator <=128.
__global__ __launch_bounds__(256, 4)
void gsl_mfma(const float* __restrict__ x,
              const float* __restrict__ trans_w, const float* __restrict__ trans_g,
              const float* __restrict__ trans_b, const float* __restrict__ trans_m,
              const float* __restrict__ trans_v,
              const float* __restrict__ pos_w1, const float* __restrict__ pos_g,
              const float* __restrict__ pos_b, const float* __restrict__ pos_m,
              const float* __restrict__ pos_v, const float* __restrict__ pos_w2,
              const float* __restrict__ pos_b2,
              const float* __restrict__ gate_w1, const float* __restrict__ gate_g,
              const float* __restrict__ gate_b, const float* __restrict__ gate_m,
              const float* __restrict__ gate_v, const float* __restrict__ gate_w2,
              const float* __restrict__ gate_b2,
              const float* __restrict__ attn_w1, const float* __restrict__ attn_g,
              const float* __restrict__ attn_b, const float* __restrict__ attn_m,
              const float* __restrict__ attn_v, const float* __restrict__ attn_w2,
              const float* __restrict__ attn_b2,
              float* __restrict__ out)
{
    __shared__ _Float16 WH[1920];        // WP1 4x(16x20) | WA1 16x20 | WG1 16x20
    __shared__ _Float16 W2L[5120];       // pos_w2 A-frags: 8 tiles x 16p x stride40
    __shared__ float    PB2[64];
    __shared__ _Float16 PHB[4][2][1152]; // per-wave dbuf: 16 pts x stride 72
    __shared__ _Float16 AHB[4][2][320];  // per-wave dbuf: 16 pts x stride 20

    const int tid  = threadIdx.x;
    const int wv   = tid >> 6;
    const int lane = tid & 63;
    const int p    = lane & 15;
    const int q    = lane >> 4;

    const int b  = blockIdx.x >> 7;
    const int n0 = ((blockIdx.x & 127) << 6) | (wv << 4);
    const int n  = n0 | p;

    // ---- stage pos_w2 A-frag layout into W2L (one-time, contiguous reads) ----
    #pragma unroll
    for (int e = 0; e < 16; ++e) {
        int idx = tid * 16 + e;              // 4096 elements
        int t   = idx >> 9;                  // tile (mt*2+h)
        int rem = idx & 511;
        int pp  = rem >> 5;
        int ii  = rem & 31;
        W2L[t * 640 + pp * 40 + ii] =
            (_Float16)pos_w2[((t >> 1) * 16 + pp) * 64 + (t & 1) * 32 + ii];
    }

    // ---- stage produce-side weights in block-shared LDS (rows stride 20h) ----
    if (tid < 64) {
        const int c = tid;
        float sp = pos_g[c] * rsqrtf(pos_v[c] + EPSV);
        float bp = pos_b[c] - pos_m[c] * sp;
        _Float16* row = WH + (c >> 4) * 320 + (c & 15) * 20;
        for (int k = 0; k < 20; ++k) {
            float v = (k >= 3 && k < 6) ? pos_w1[c * 3 + (k - 3)] * sp
                                        : ((k == 6) ? bp : 0.f);
            row[k] = (_Float16)v;
        }
        PB2[c] = pos_b2[c];
    } else if (tid < 80) {
        const int j = tid - 64;
        float sa = attn_g[j] * rsqrtf(attn_v[j] + EPSV);
        float ba = attn_b[j] - attn_m[j] * sa;
        _Float16* row = WH + 1280 + j * 20;
        for (int k = 0; k < 20; ++k)
            row[k] = (_Float16)((k < 6) ? attn_w1[j * 6 + k] * sa
                                        : ((k == 6) ? ba : 0.f));
    } else if (tid < 96) {
        const int j = tid - 80;
        float sg = gate_g[j] * rsqrtf(gate_v[j] + EPSV);
        float bg = gate_b[j] - gate_m[j] * sg;
        _Float16* row = WH + 1600 + j * 20;
        for (int k = 0; k < 20; ++k)
            row[k] = (_Float16)((k < 6) ? gate_w1[j * 6 + k] * sg
                                        : ((k == 6) ? bg : 0.f));
    }

    // ---- persistent A-frags: WTf/WA2f (K=16, 2 VGPRs each) + WG2f broadcast ----
    v4h WTf[4], WA2f[4], WG2f;
    #pragma unroll
    for (int mt = 0; mt < 4; ++mt) {
        const int ch = mt * 16 + p;
        #pragma unroll
        for (int i = 0; i < 4; ++i)
            WA2f[mt][i] = (_Float16)attn_w2[ch * 16 + q * 4 + i];
        float st = trans_g[ch] * rsqrtf(trans_v[ch] + EPSV);
        float bt = trans_b[ch] - trans_m[ch] * st;
        #pragma unroll
        for (int i = 0; i < 4; ++i) {
            int k = q * 4 + i;
            float v = (k < 6) ? trans_w[ch * 6 + k] * st : ((k == 6) ? bt : 0.f);
            WTf[mt][i] = (_Float16)v;
        }
    }
    #pragma unroll
    for (int i = 0; i < 4; ++i)
        WG2f[i] = (_Float16)gate_w2[4 * q + i];   // A[row][k]=gate_w2[k] broadcast
    const float gb2v = gate_b2[0];

    __syncthreads();   // W2L/WH/PB2 visible to all waves

    const _Float16* const WP1p = WH + p * 20 + q * 4;          // + mt*320
    const _Float16* const WA1p = WH + 1280 + p * 20 + q * 4;
    const _Float16* const WG1p = WH + 1600 + p * 20 + q * 4;
    const _Float16* const W2Lp = W2L + p * 40 + q * 8;         // + tile*640
    const float* const    PB2p = PB2 + 4 * q;                  // + mt*16

    _Float16* const PHbase = &PHB[wv][0][0];
    _Float16* const AHbase = &AHB[wv][0][0];
    _Float16* const PH0 = PHbase;            // even-k buffer
    _Float16* const PH1 = PHbase + 1152;     // odd-k buffer
    _Float16* const AH0 = AHbase;
    _Float16* const AH1 = AHbase + 320;

    const v4f zero = {0.f, 0.f, 0.f, 0.f};
    v4f den[4], num[4], cmx[4];
    #pragma unroll
    for (int mt = 0; mt < 4; ++mt) {
        den[mt] = zero; num[mt] = zero;
        cmx[mt] = (v4f){-3.4e38f, -3.4e38f, -3.4e38f, -3.4e38f};
    }

    // ---- per-lane channel streams (k-contiguous rows of 20 floats) ----
    const int hi = q & 1;   // q>=2 dups q&1 (A-side k>=8 rows are zero)
    const float* pA = x + ((size_t)(b * 6 + (hi ? 4 : 0)) * 8192 + n) * 20;
    const float* pB = x + ((size_t)(b * 6 + (hi ? 5 : 1)) * 8192 + n) * 20;
    const float* pC = x + ((size_t)(b * 6 + (hi ? 4 : 2)) * 8192 + n) * 20;
    const float* pD = x + ((size_t)(b * 6 + (hi ? 5 : 3)) * 8192 + n) * 20;

    // build B-frag for one k; hi lanes supply (cA,cB,1,0)
    auto mk = [&](float a, float bb, float cc, float dd) -> v4h {
        v2h lo = pk(a, bb);
        v2h hh = pk(cc, dd);
        if (hi) { union { unsigned u; v2h h; } t; t.u = 0x00003C00u; hh = t.h; }
        return (v4h){lo.x, lo.y, hh.x, hh.y};
    };

    auto PRODUCE = [&](v4h xv, _Float16* PHW, _Float16* AHW) {
        v4f php[4];
        #pragma unroll
        for (int mt = 0; mt < 4; ++mt)
            php[mt] = MFMA16(*(const v4h*)(WP1p + mt * 320), xv, zero);
        v4f ahp = MFMA16(*(const v4h*)WA1p, xv, zero);
        #pragma unroll
        for (int mt = 0; mt < 4; ++mt) {
            union { v4h v; v2h h[2]; } u;
            u.h[0] = lreluh2(pk(php[mt][0], php[mt][1]));
            u.h[1] = lreluh2(pk(php[mt][2], php[mt][3]));
            *(v4h*)(PHW + mt * 16) = u.v;
        }
        union { v4h v; v2h h[2]; } ua;
        ua.h[0] = lreluh2(pk(ahp[0], ahp[1]));
        ua.h[1] = lreluh2(pk(ahp[2], ahp[3]));
        *(v4h*)AHW = ua.v;
    };

    auto CONSUME = [&](v4h xv, v8h phf0, v8h phf1, v4h ahf) {
        // gate: MFMA reduction (no shuffles). ghp is already B-layout.
        v4f ghp = MFMA16(*(const v4h*)WG1p, xv, zero);
        union { v4h v; v2h h[2]; } ug;
        ug.h[0] = lreluh2(pk(ghp[0], ghp[1]));
        ug.h[1] = lreluh2(pk(ghp[2], ghp[3]));
        v4f gav = MFMA16(WG2f, ug.v, zero);
        const float gate = 1.f / (1.f + __expf(-(gav[0] + gb2v)));

        // per-mt streaming: W2 frags re-read from LDS each iter (clobber holds)
        #pragma unroll
        for (int mt = 0; mt < 4; ++mt) {
            v8h w2a = *(const v8h*)(W2Lp + (mt * 2 + 0) * 640);
            v8h w2b = *(const v8h*)(W2Lp + (mt * 2 + 1) * 640);
            v4f pe = MFMA32(w2a, phf0, *(const v4f*)(PB2p + mt * 16));
            pe = MFMA32(w2b, phf1, pe);
            v4f tfa = MFMA16(WTf[mt], xv, zero);
            v4f tfv = lrelu4(tfa) + pe;
            pe = MFMA16(WA2f[mt], ahf, pe);   // logits (K=16)
            v4f e;
            #pragma unroll
            for (int r = 0; r < 4; ++r) e[r] = __expf(pe[r]);
            den[mt] += e;
            num[mt] += tfv * e;
            cmx[mt] = __builtin_elementwise_max(cmx[mt], tfv * gate);
        }
    };

    // ---- prologue: group 0 loads, produce(k=0) into even buffer ----
    float2 cA = *(const float2*)pA;
    float2 cB = *(const float2*)pB;
    float2 cC = *(const float2*)pC;
    float2 cD = *(const float2*)pD;
    v4h xvE = mk(cA.x, cB.x, cC.x, cD.x);
    PRODUCE(xvE, PH0 + p * 72 + 4 * q, AH0 + p * 20 + 4 * q);

    #pragma unroll 1
    for (int g = 0; g < 10; ++g) {
        // prevent LICM from hoisting in-loop LDS weight reads into registers
        asm volatile("" ::: "memory");

        // prefetch next k-pair group (registers; latency hides under compute)
        float2 nA = cA, nB = cB, nC = cC, nD = cD;
        if (g < 9) {
            const int o = 2 * g + 2;
            nA = *(const float2*)(pA + o);
            nB = *(const float2*)(pB + o);
            nC = *(const float2*)(pC + o);
            nD = *(const float2*)(pD + o);
        }

        // ---- k = 2g (even): read PH0, produce k+1 -> PH1 ----
        v8h phf0 = *(const v8h*)(PH0 + p * 72 + 8 * q);
        v8h phf1 = *(const v8h*)(PH0 + p * 72 + 32 + 8 * q);
        v4h ahf  = *(const v4h*)(AH0 + p * 20 + 4 * q);
        v4h xvO = mk(cA.y, cB.y, cC.y, cD.y);
        PRODUCE(xvO, PH1 + p * 72 + 4 * q, AH1 + p * 20 + 4 * q);
        CONSUME(xvE, phf0, phf1, ahf);

        // ---- k = 2g+1 (odd): read PH1, produce k+2 -> PH0 ----
        phf0 = *(const v8h*)(PH1 + p * 72 + 8 * q);
        phf1 = *(const v8h*)(PH1 + p * 72 + 32 + 8 * q);
        ahf  = *(const v4h*)(AH1 + p * 20 + 4 * q);
        if (g < 9) {
            xvE = mk(nA.x, nB.x, nC.x, nD.x);
            PRODUCE(xvE, PH0 + p * 72 + 4 * q, AH0 + p * 20 + 4 * q);
        }
        CONSUME(xvO, phf0, phf1, ahf);

        cA = nA; cB = nB; cC = nC; cD = nD;
    }

    // write out: lane owns channels mt*16 + 4q + r for its point n
    #pragma unroll
    for (int mt = 0; mt < 4; ++mt) {
        #pragma unroll
        for (int r = 0; r < 4; ++r) {
            const int ch = mt * 16 + 4 * q + r;
            out[((size_t)(b * 64 + ch)) * 8192 + n] =
                num[mt][r] / den[mt][r] + cmx[mt][r];
        }
    }
}

extern "C" void kernel_launch(void* const* d_in, const int* in_sizes, int n_in,
                              void* d_out, int out_size, void* d_ws, size_t ws_size,
                              hipStream_t stream) {
    const float* x       = (const float*)d_in[0];
    const float* trans_w = (const float*)d_in[1];
    const float* trans_g = (const float*)d_in[2];
    const float* trans_b = (const float*)d_in[3];
    const float* trans_m = (const float*)d_in[4];
    const float* trans_v = (const float*)d_in[5];
    const float* pos_w1  = (const float*)d_in[6];
    const float* pos_g   = (const float*)d_in[7];
    const float* pos_b   = (const float*)d_in[8];
    const float* pos_m   = (const float*)d_in[9];
    const float* pos_v   = (const float*)d_in[10];
    const float* pos_w2  = (const float*)d_in[11];
    const float* pos_b2  = (const float*)d_in[12];
    const float* gate_w1 = (const float*)d_in[13];
    const float* gate_g  = (const float*)d_in[14];
    const float* gate_b  = (const float*)d_in[15];
    const float* gate_m  = (const float*)d_in[16];
    const float* gate_v  = (const float*)d_in[17];
    const float* gate_w2 = (const float*)d_in[18];
    const float* gate_b2 = (const float*)d_in[19];
    const float* attn_w1 = (const float*)d_in[20];
    const float* attn_g  = (const float*)d_in[21];
    const float* attn_b  = (const float*)d_in[22];
    const float* attn_m  = (const float*)d_in[23];
    const float* attn_v  = (const float*)d_in[24];
    const float* attn_w2 = (const float*)d_in[25];
    const float* attn_b2 = (const float*)d_in[26];
    float* out = (float*)d_out;

    // 8 b * 128 blocks/b; block = 4 waves * 16 points
    gsl_mfma<<<1024, 256, 0, stream>>>(
        x, trans_w, trans_g, trans_b, trans_m, trans_v,
        pos_w1, pos_g, pos_b, pos_m, pos_v, pos_w2, pos_b2,
        gate_w1, gate_g, gate_b, gate_m, gate_v, gate_w2, gate_b2,
        attn_w1, attn_g, attn_b, attn_m, attn_v, attn_w2, attn_b2,
        out);
}

// Round 2
// 175.596 us; speedup vs baseline: 2.3381x; 2.3381x over previous
//
#include <hip/hip_runtime.h>
#include <math.h>

#define NEG 0.2f
#define EPSV 1e-5f

typedef _Float16 v8h __attribute__((ext_vector_type(8)));
typedef _Float16 v4h __attribute__((ext_vector_type(4)));
typedef _Float16 v2h __attribute__((ext_vector_type(2)));
typedef __fp16   f16x2 __attribute__((ext_vector_type(2)));
typedef float    v4f __attribute__((ext_vector_type(4)));

__device__ __forceinline__ float lrelu(float v) { return fmaxf(v, NEG * v); }
__device__ __forceinline__ v4f lrelu4(v4f v) {
    return __builtin_elementwise_max(v, v * NEG);
}
__device__ __forceinline__ v2h lreluh2(v2h v) {
    return __builtin_elementwise_max(v, v * (_Float16)NEG);
}

// cvt_pkrtz returns __fp16x2; bit-cast to _Float16x2 (same layout)
__device__ __forceinline__ v2h pk(float a, float b) {
    union { f16x2 i; v2h o; } u;
    u.i = __builtin_amdgcn_cvt_pkrtz(a, b);
    return u.o;
}

#define MFMA32(a, b, c) __builtin_amdgcn_mfma_f32_16x16x32_f16((a), (b), (c), 0, 0, 0)
#define MFMA16(a, b, c) __builtin_amdgcn_mfma_f32_16x16x16f16((a), (b), (c), 0, 0, 0)

// Round 16: R15 spilled (FETCH 665MB / WRITE 717MB = scratch round-trips:
// x2 unroll doubled live temporaries while launch_bounds(256,4) cut the VGPR
// budget 170->128). Revert to the proven R14 structure (sel-loop, (256,3))
// and keep only the two register-neutral wins from R15:
// (1) Gate reduction via MFMA (ghp is already B-operand layout): one MFMA with
//     broadcast A-frag A[row][k]=gate_w2[k] replaces 2 serial __shfl_xor +
//     ~10 VALU per k. Numerics verified in R15 (same absmax).
// (2) 4 per-lane channel streams instead of 6 (hi lanes re-read c4/c5, L1-hit);
//     B-frag hi half = one cndmask'd constant (1.0, 0.0).
__global__ __launch_bounds__(256, 3)
void gsl_mfma(const float* __restrict__ x,
              const float* __restrict__ trans_w, const float* __restrict__ trans_g,
              const float* __restrict__ trans_b, const float* __restrict__ trans_m,
              const float* __restrict__ trans_v,
              const float* __restrict__ pos_w1, const float* __restrict__ pos_g,
              const float* __restrict__ pos_b, const float* __restrict__ pos_m,
              const float* __restrict__ pos_v, const float* __restrict__ pos_w2,
              const float* __restrict__ pos_b2,
              const float* __restrict__ gate_w1, const float* __restrict__ gate_g,
              const float* __restrict__ gate_b, const float* __restrict__ gate_m,
              const float* __restrict__ gate_v, const float* __restrict__ gate_w2,
              const float* __restrict__ gate_b2,
              const float* __restrict__ attn_w1, const float* __restrict__ attn_g,
              const float* __restrict__ attn_b, const float* __restrict__ attn_m,
              const float* __restrict__ attn_v, const float* __restrict__ attn_w2,
              const float* __restrict__ attn_b2,
              float* __restrict__ out)
{
    __shared__ _Float16 WH[1920];        // WP1 4x(16x20) | WA1 16x20 | WG1 16x20
    __shared__ _Float16 W2L[5120];       // pos_w2 A-frags: 8 tiles x 16p x stride40
    __shared__ float    PB2[64];
    __shared__ _Float16 PHB[4][2][1152]; // per-wave dbuf: 16 pts x stride 72
    __shared__ _Float16 AHB[4][2][320];  // per-wave dbuf: 16 pts x stride 20

    const int tid  = threadIdx.x;
    const int wv   = tid >> 6;
    const int lane = tid & 63;
    const int p    = lane & 15;
    const int q    = lane >> 4;

    const int b  = blockIdx.x >> 7;
    const int n0 = ((blockIdx.x & 127) << 6) | (wv << 4);
    const int n  = n0 | p;

    // ---- stage pos_w2 A-frag layout into W2L (one-time, contiguous reads) ----
    #pragma unroll
    for (int e = 0; e < 16; ++e) {
        int idx = tid * 16 + e;              // 4096 elements
        int t   = idx >> 9;                  // tile (mt*2+h)
        int rem = idx & 511;
        int pp  = rem >> 5;
        int ii  = rem & 31;
        W2L[t * 640 + pp * 40 + ii] =
            (_Float16)pos_w2[((t >> 1) * 16 + pp) * 64 + (t & 1) * 32 + ii];
    }

    // ---- stage produce-side weights in block-shared LDS (rows stride 20h) ----
    if (tid < 64) {
        const int c = tid;
        float sp = pos_g[c] * rsqrtf(pos_v[c] + EPSV);
        float bp = pos_b[c] - pos_m[c] * sp;
        _Float16* row = WH + (c >> 4) * 320 + (c & 15) * 20;
        for (int k = 0; k < 20; ++k) {
            float v = (k >= 3 && k < 6) ? pos_w1[c * 3 + (k - 3)] * sp
                                        : ((k == 6) ? bp : 0.f);
            row[k] = (_Float16)v;
        }
        PB2[c] = pos_b2[c];
    } else if (tid < 80) {
        const int j = tid - 64;
        float sa = attn_g[j] * rsqrtf(attn_v[j] + EPSV);
        float ba = attn_b[j] - attn_m[j] * sa;
        _Float16* row = WH + 1280 + j * 20;
        for (int k = 0; k < 20; ++k)
            row[k] = (_Float16)((k < 6) ? attn_w1[j * 6 + k] * sa
                                        : ((k == 6) ? ba : 0.f));
    } else if (tid < 96) {
        const int j = tid - 80;
        float sg = gate_g[j] * rsqrtf(gate_v[j] + EPSV);
        float bg = gate_b[j] - gate_m[j] * sg;
        _Float16* row = WH + 1600 + j * 20;
        for (int k = 0; k < 20; ++k)
            row[k] = (_Float16)((k < 6) ? gate_w1[j * 6 + k] * sg
                                        : ((k == 6) ? bg : 0.f));
    }

    // ---- persistent A-frags: WTf/WA2f (K=16, 2 VGPRs each) + WG2f broadcast ----
    v4h WTf[4], WA2f[4], WG2f;
    #pragma unroll
    for (int mt = 0; mt < 4; ++mt) {
        const int ch = mt * 16 + p;
        #pragma unroll
        for (int i = 0; i < 4; ++i)
            WA2f[mt][i] = (_Float16)attn_w2[ch * 16 + q * 4 + i];
        float st = trans_g[ch] * rsqrtf(trans_v[ch] + EPSV);
        float bt = trans_b[ch] - trans_m[ch] * st;
        #pragma unroll
        for (int i = 0; i < 4; ++i) {
            int k = q * 4 + i;
            float v = (k < 6) ? trans_w[ch * 6 + k] * st : ((k == 6) ? bt : 0.f);
            WTf[mt][i] = (_Float16)v;
        }
    }
    #pragma unroll
    for (int i = 0; i < 4; ++i)
        WG2f[i] = (_Float16)gate_w2[4 * q + i];   // A[row][k]=gate_w2[k] broadcast
    const float gb2v = gate_b2[0];

    __syncthreads();   // W2L/WH/PB2 visible to all waves

    const _Float16* const WP1p = WH + p * 20 + q * 4;          // + mt*320
    const _Float16* const WA1p = WH + 1280 + p * 20 + q * 4;
    const _Float16* const WG1p = WH + 1600 + p * 20 + q * 4;
    const _Float16* const W2Lp = W2L + p * 40 + q * 8;         // + tile*640
    const float* const    PB2p = PB2 + 4 * q;                  // + mt*16

    _Float16* const PHbase = &PHB[wv][0][0];
    _Float16* const AHbase = &AHB[wv][0][0];

    const v4f zero = {0.f, 0.f, 0.f, 0.f};
    v4f den[4], num[4], cmx[4];
    #pragma unroll
    for (int mt = 0; mt < 4; ++mt) {
        den[mt] = zero; num[mt] = zero;
        cmx[mt] = (v4f){-3.4e38f, -3.4e38f, -3.4e38f, -3.4e38f};
    }

    // ---- per-lane channel streams (only the 4 this lane consumes) ----
    const float* xb = x + ((size_t)(b * 6) * 8192 + n) * 20;
    const int hi = q & 1;   // q>=2 dups q&1 (A-side k>=8 rows are zero)
    const float* const s0p = xb + (size_t)(hi ? 4 : 0) * 163840;
    const float* const s1p = xb + (size_t)(hi ? 5 : 1) * 163840;
    const float* const s2p = xb + (size_t)(hi ? 4 : 2) * 163840;  // hi: L1 dup
    const float* const s3p = xb + (size_t)(hi ? 5 : 3) * 163840;  // hi: L1 dup

    // build v4h B-frag; hi lanes' high half is the constant (1.0, 0.0)
    auto mk = [&](float a, float bb, float cc, float dd) -> v4h {
        v2h lo = pk(a, bb);
        v2h hh = pk(cc, dd);
        if (hi) { union { unsigned u; v2h h; } t; t.u = 0x00003C00u; hh = t.h; }
        return (v4h){lo.x, lo.y, hh.x, hh.y};
    };

    float nx0 = s0p[0], nx1 = s1p[0], nx2 = s2p[0], nx3 = s3p[0];
    v4h xv_cur = mk(nx0, nx1, nx2, nx3);
    nx0 = s0p[1]; nx1 = s1p[1]; nx2 = s2p[1]; nx3 = s3p[1];

    {   // produce(0) into buffer 0
        v4f php[4];
        #pragma unroll
        for (int mt = 0; mt < 4; ++mt)
            php[mt] = MFMA16(*(const v4h*)(WP1p + mt * 320), xv_cur, zero);
        v4f ahp = MFMA16(*(const v4h*)WA1p, xv_cur, zero);
        _Float16* PHW = PHbase + p * 72 + 4 * q;
        #pragma unroll
        for (int mt = 0; mt < 4; ++mt) {
            union { v4h v; v2h h[2]; } u;
            u.h[0] = lreluh2(pk(php[mt][0], php[mt][1]));
            u.h[1] = lreluh2(pk(php[mt][2], php[mt][3]));
            *(v4h*)(PHW + mt * 16) = u.v;
        }
        union { v4h v; v2h h[2]; } ua;
        ua.h[0] = lreluh2(pk(ahp[0], ahp[1]));
        ua.h[1] = lreluh2(pk(ahp[2], ahp[3]));
        *(v4h*)(AHbase + p * 20 + 4 * q) = ua.v;
    }

    #pragma unroll 1
    for (int k = 0; k < 20; ++k) {
        // prevent LICM from hoisting in-loop LDS weight reads into registers
        asm volatile("" ::: "memory");

        const int sel = k & 1;
        // 1) issue reads for k (writes landed last iteration)
        _Float16* PH = PHbase + sel * 1152;
        _Float16* AH = AHbase + sel * 320;
        v8h phf0 = *(const v8h*)(PH + p * 72 + 8 * q);
        v8h phf1 = *(const v8h*)(PH + p * 72 + 32 + 8 * q);
        v4h ahf  = *(const v4h*)(AH + p * 20 + 4 * q);

        // 2) produce(k+1) into the other buffer
        v4h xv_nxt = xv_cur;
        if (k < 19) {
            xv_nxt = mk(nx0, nx1, nx2, nx3);
            const int kn = (k < 18) ? k + 2 : 19;
            nx0 = s0p[kn]; nx1 = s1p[kn]; nx2 = s2p[kn]; nx3 = s3p[kn];

            v4f php[4];
            #pragma unroll
            for (int mt = 0; mt < 4; ++mt)
                php[mt] = MFMA16(*(const v4h*)(WP1p + mt * 320), xv_nxt, zero);
            v4f ahp = MFMA16(*(const v4h*)WA1p, xv_nxt, zero);
            _Float16* PHW = PHbase + (sel ^ 1) * 1152 + p * 72 + 4 * q;
            #pragma unroll
            for (int mt = 0; mt < 4; ++mt) {
                union { v4h v; v2h h[2]; } uu;
                uu.h[0] = lreluh2(pk(php[mt][0], php[mt][1]));
                uu.h[1] = lreluh2(pk(php[mt][2], php[mt][3]));
                *(v4h*)(PHW + mt * 16) = uu.v;
            }
            union { v4h v; v2h h[2]; } ua;
            ua.h[0] = lreluh2(pk(ahp[0], ahp[1]));
            ua.h[1] = lreluh2(pk(ahp[2], ahp[3]));
            *(v4h*)(AHbase + (sel ^ 1) * 320 + p * 20 + 4 * q) = ua.v;
        }

        // 3) consume(k): gate via MFMA reduction (no serial shuffles)
        v4f ghp = MFMA16(*(const v4h*)WG1p, xv_cur, zero);
        union { v4h v; v2h h[2]; } ug;
        ug.h[0] = lreluh2(pk(ghp[0], ghp[1]));
        ug.h[1] = lreluh2(pk(ghp[2], ghp[3]));
        v4f gav = MFMA16(WG2f, ug.v, zero);
        const float gate = 1.f / (1.f + __expf(-(gav[0] + gb2v)));

        // per-mt streaming: W2 frags re-read from LDS each iter (clobber holds)
        #pragma unroll
        for (int mt = 0; mt < 4; ++mt) {
            v8h w2a = *(const v8h*)(W2Lp + (mt * 2 + 0) * 640);
            v8h w2b = *(const v8h*)(W2Lp + (mt * 2 + 1) * 640);
            v4f pe = MFMA32(w2a, phf0, *(const v4f*)(PB2p + mt * 16));
            pe = MFMA32(w2b, phf1, pe);
            v4f tfa = MFMA16(WTf[mt], xv_cur, zero);
            v4f tfv = lrelu4(tfa) + pe;
            pe = MFMA16(WA2f[mt], ahf, pe);   // logits (K=16)
            v4f e;
            #pragma unroll
            for (int r = 0; r < 4; ++r) e[r] = __expf(pe[r]);
            den[mt] += e;
            num[mt] += tfv * e;
            cmx[mt] = __builtin_elementwise_max(cmx[mt], tfv * gate);
        }
        xv_cur = xv_nxt;
    }

    // write out: lane owns channels mt*16 + 4q + r for its point n
    #pragma unroll
    for (int mt = 0; mt < 4; ++mt) {
        #pragma unroll
        for (int r = 0; r < 4; ++r) {
            const int ch = mt * 16 + 4 * q + r;
            out[((size_t)(b * 64 + ch)) * 8192 + n] =
                num[mt][r] / den[mt][r] + cmx[mt][r];
        }
    }
}

extern "C" void kernel_launch(void* const* d_in, const int* in_sizes, int n_in,
                              void* d_out, int out_size, void* d_ws, size_t ws_size,
                              hipStream_t stream) {
    const float* x       = (const float*)d_in[0];
    const float* trans_w = (const float*)d_in[1];
    const float* trans_g = (const float*)d_in[2];
    const float* trans_b = (const float*)d_in[3];
    const float* trans_m = (const float*)d_in[4];
    const float* trans_v = (const float*)d_in[5];
    const float* pos_w1  = (const float*)d_in[6];
    const float* pos_g   = (const float*)d_in[7];
    const float* pos_b   = (const float*)d_in[8];
    const float* pos_m   = (const float*)d_in[9];
    const float* pos_v   = (const float*)d_in[10];
    const float* pos_w2  = (const float*)d_in[11];
    const float* pos_b2  = (const float*)d_in[12];
    const float* gate_w1 = (const float*)d_in[13];
    const float* gate_g  = (const float*)d_in[14];
    const float* gate_b  = (const float*)d_in[15];
    const float* gate_m  = (const float*)d_in[16];
    const float* gate_v  = (const float*)d_in[17];
    const float* gate_w2 = (const float*)d_in[18];
    const float* gate_b2 = (const float*)d_in[19];
    const float* attn_w1 = (const float*)d_in[20];
    const float* attn_g  = (const float*)d_in[21];
    const float* attn_b  = (const float*)d_in[22];
    const float* attn_m  = (const float*)d_in[23];
    const float* attn_v  = (const float*)d_in[24];
    const float* attn_w2 = (const float*)d_in[25];
    const float* attn_b2 = (const float*)d_in[26];
    float* out = (float*)d_out;

    // 8 b * 128 blocks/b; block = 4 waves * 16 points
    gsl_mfma<<<1024, 256, 0, stream>>>(
        x, trans_w, trans_g, trans_b, trans_m, trans_v,
        pos_w1, pos_g, pos_b, pos_m, pos_v, pos_w2, pos_b2,
        gate_w1, gate_g, gate_b, gate_m, gate_v, gate_w2, gate_b2,
        attn_w1, attn_g, attn_b, attn_m, attn_v, attn_w2, attn_b2,
        out);
}